// Round 3
// baseline (17.772 us; speedup 1.0000x reference)
//
#include <hip/hip_runtime.h>

#define DD 200
#define UU 32
#define TT 4
#define AA 20
#define NN 10
#define WPB 4          // waves (batch elements) per block

// per-wave LDS float layout:
//   nte:    [0, 144)    4 rows of stride 36 (bank-conflict-free, 16B aligned)
//   h:      [144, 224)  4*20
//   logits: [224, 228)
#define NTE_STRIDE 36
#define H_OFF 144
#define LG_OFF 224
#define WS_FLOATS 240

__device__ __forceinline__ float readlane_f(float v, int l) {
    return __int_as_float(__builtin_amdgcn_readlane(__float_as_int(v), l));
}

__device__ __forceinline__ float tanh_fast(float x) {
    // 1 - 2/(e^{2x}+1): v_exp + v_rcp, saturates correctly at +-inf
    const float e = __expf(2.f * x);
    return 1.f - 2.f / (e + 1.f);
}

__global__ __launch_bounds__(256) void gatne_kernel(
    const int* __restrict__ train_inputs,
    const int* __restrict__ train_types,
    const int* __restrict__ node_neigh,
    const float* __restrict__ node_emb,
    const float* __restrict__ node_type_emb,
    const float* __restrict__ trans_w,
    const float* __restrict__ trans_s1,
    const float* __restrict__ trans_s2,
    float* __restrict__ out,
    int B)
{
    const int tid  = threadIdx.x;
    const int wid  = tid >> 6;
    const int lane = tid & 63;
    const int b    = blockIdx.x * WPB + wid;

    __shared__ float smem[WPB][WS_FLOATS];
    float* ws = smem[wid];

    if (b >= B) return;   // wave-uniform

    const int type  = train_types[b];
    const int input = train_inputs[b];

    // ---- early independent load: node_emb row (overlaps the whole gather) ----
    float4 o = make_float4(0.f, 0.f, 0.f, 0.f);
    if (lane < DD / 4)
        o = *(const float4*)(node_emb + (size_t)input * DD + lane * 4);

    // ---- gather mapping: 8 lanes per 128B row ----
    const int g    = lane >> 3;        // 0..7
    const int sub  = lane & 7;
    const int gt   = g >> 1;           // t
    const int nb   = (g & 1) * 5;      // n-half base

    // each lane loads its own 5 neighbor indices (broadcast within 8-lane groups)
    const int* nrow = node_neigh + (size_t)b * (TT * NN) + gt * NN + nb;
    int nidx[5];
    #pragma unroll
    for (int i = 0; i < 5; ++i) nidx[i] = nrow[i];

    // ---- gather neighbor type-embeddings, sum over N ----
    float4 acc = make_float4(0.f, 0.f, 0.f, 0.f);
    #pragma unroll
    for (int i = 0; i < 5; ++i) {
        const unsigned off = (unsigned)nidx[i] * (TT * UU) + gt * UU + sub * 4;
        const float4 v = *(const float4*)(node_type_emb + off);
        acc.x += v.x; acc.y += v.y; acc.z += v.z; acc.w += v.w;
    }
    acc.x += __shfl_xor(acc.x, 8);
    acc.y += __shfl_xor(acc.y, 8);
    acc.z += __shfl_xor(acc.z, 8);
    acc.w += __shfl_xor(acc.w, 8);
    if ((g & 1) == 0)
        *(float4*)(ws + gt * NTE_STRIDE + sub * 4) = acc;
    asm volatile("s_waitcnt lgkmcnt(0)" ::: "memory");

    // ---- h[t][a] = tanh( sum_u nte[t][u] * s1[u][a] ) ----
    const float* s1g = trans_s1 + (size_t)type * (UU * AA);
    {
        const int t = lane >> 4, a = lane & 15;          // a = 0..15
        float hacc = 0.f;
        #pragma unroll
        for (int u = 0; u < UU; ++u)
            hacc += ws[t * NTE_STRIDE + u] * s1g[u * AA + a];
        ws[H_OFF + t * AA + a] = tanh_fast(hacc);
    }
    if (lane < 16) {                                     // a = 16..19
        const int t = lane >> 2, a = 16 + (lane & 3);
        float hacc = 0.f;
        #pragma unroll
        for (int u = 0; u < UU; ++u)
            hacc += ws[t * NTE_STRIDE + u] * s1g[u * AA + a];
        ws[H_OFF + t * AA + a] = tanh_fast(hacc);
    }
    asm volatile("s_waitcnt lgkmcnt(0)" ::: "memory");

    // ---- logits[t] = h[t] . s2 ----
    if (lane < TT) {
        const float* s2g = trans_s2 + (size_t)type * AA;
        float lacc = 0.f;
        #pragma unroll
        for (int k = 0; k < 5; ++k) {
            const float4 h4 = *(const float4*)(ws + H_OFF + lane * AA + 4 * k);
            const float4 s4 = *(const float4*)(s2g + 4 * k);
            lacc += h4.x * s4.x + h4.y * s4.y + h4.z * s4.z + h4.w * s4.w;
        }
        ws[LG_OFF + lane] = lacc;
    }
    asm volatile("s_waitcnt lgkmcnt(0)" ::: "memory");

    // ---- softmax over T=4 (redundant in every lane) ----
    const float4 lg = *(const float4*)(ws + LG_OFF);
    const float m  = fmaxf(fmaxf(lg.x, lg.y), fmaxf(lg.z, lg.w));
    float e0 = __expf(lg.x - m), e1 = __expf(lg.y - m),
          e2 = __expf(lg.z - m), e3 = __expf(lg.w - m);
    const float inv = 1.f / (e0 + e1 + e2 + e3);
    e0 *= inv; e1 *= inv; e2 *= inv; e3 *= inv;

    // ---- agg[u], u = lane&31 (duplicated across half-waves) ----
    const int u = lane & 31;
    const float aggu = e0 * ws[0 * NTE_STRIDE + u] + e1 * ws[1 * NTE_STRIDE + u]
                     + e2 * ws[2 * NTE_STRIDE + u] + e3 * ws[3 * NTE_STRIDE + u];

    // ---- out = node_emb[input] + agg @ trans_w[type]; L2 normalize ----
    float4 o2 = make_float4(0.f, 0.f, 0.f, 0.f);
    const float* wg = trans_w + (size_t)type * (UU * DD);
    if (lane < DD / 4) {      // 50 lanes, d0 = lane*4
        const unsigned dbase = (unsigned)(lane * 4);
        #pragma unroll
        for (int uu = 0; uu < UU; uu += 2) {
            const float a0 = readlane_f(aggu, uu);
            const float a1 = readlane_f(aggu, uu + 1);
            const float4 w0 = *(const float4*)(wg + uu * DD + dbase);
            const float4 w1 = *(const float4*)(wg + (uu + 1) * DD + dbase);
            o.x  += a0 * w0.x; o.y  += a0 * w0.y; o.z  += a0 * w0.z; o.w  += a0 * w0.w;
            o2.x += a1 * w1.x; o2.y += a1 * w1.y; o2.z += a1 * w1.z; o2.w += a1 * w1.w;
        }
        o.x += o2.x; o.y += o2.y; o.z += o2.z; o.w += o2.w;
    }
    float sq = o.x * o.x + o.y * o.y + o.z * o.z + o.w * o.w;
    #pragma unroll
    for (int off = 1; off < 64; off <<= 1) sq += __shfl_xor(sq, off);
    const float invn = 1.f / fmaxf(sqrtf(sq), 1e-12f);
    if (lane < DD / 4) {
        const float4 r = make_float4(o.x * invn, o.y * invn, o.z * invn, o.w * invn);
        *(float4*)(out + (size_t)b * DD + lane * 4) = r;
    }
}

extern "C" void kernel_launch(void* const* d_in, const int* in_sizes, int n_in,
                              void* d_out, int out_size, void* d_ws, size_t ws_size,
                              hipStream_t stream) {
    const int*   train_inputs  = (const int*)d_in[0];
    const int*   train_types   = (const int*)d_in[1];
    const int*   node_neigh    = (const int*)d_in[2];
    const float* node_emb      = (const float*)d_in[3];
    const float* node_type_emb = (const float*)d_in[4];
    const float* trans_w       = (const float*)d_in[5];
    const float* trans_s1      = (const float*)d_in[6];
    const float* trans_s2      = (const float*)d_in[7];
    float* out = (float*)d_out;

    const int B = in_sizes[0];  // 4096
    const int grid = (B + WPB - 1) / WPB;
    gatne_kernel<<<grid, 256, 0, stream>>>(train_inputs, train_types, node_neigh,
                                           node_emb, node_type_emb, trans_w,
                                           trans_s1, trans_s2, out, B);
}

// Round 4
// 14.919 us; speedup vs baseline: 1.1912x; 1.1912x over previous
//
#include <hip/hip_runtime.h>

#define DD 200
#define UU 32
#define TT 4
#define AA 20
#define NN 10
#define WPB 4          // waves (batch elements) per block

// per-wave LDS float layout:
//   nte:    [0, 144)    4 rows of stride 36 (bank-conflict-free, 16B aligned)
//   h:      [144, 224)  4*20
//   logits: [224, 228)
#define NTE_STRIDE 36
#define H_OFF 144
#define LG_OFF 224
#define WS_FLOATS 240

__device__ __forceinline__ float tanh_fast(float x) {
    // 1 - 2/(e^{2x}+1): v_exp + v_rcp, saturates correctly at +-inf
    const float e = __expf(2.f * x);
    return 1.f - 2.f / (e + 1.f);
}

__global__ __launch_bounds__(256) void gatne_kernel(
    const int* __restrict__ train_inputs,
    const int* __restrict__ train_types,
    const int* __restrict__ node_neigh,
    const float* __restrict__ node_emb,
    const float* __restrict__ node_type_emb,
    const float* __restrict__ trans_w,
    const float* __restrict__ trans_s1,
    const float* __restrict__ trans_s2,
    float* __restrict__ out,
    int B)
{
    const int tid  = threadIdx.x;
    const int wid  = tid >> 6;
    const int lane = tid & 63;
    const int b    = blockIdx.x * WPB + wid;

    __shared__ float smem[WPB][WS_FLOATS];
    float* ws = smem[wid];

    if (b >= B) return;   // whole wave exits together (b is wave-uniform)

    // ---- per-lane gather mapping: 8 lanes per 128B row ----
    const int g    = lane >> 3;        // 0..7
    const int sub  = lane & 7;         // 0..7 (u-quad within row)
    const int gt   = g >> 1;           // this lane's t
    const int nb   = (g & 1) * 5;      // n-half base

    // lane-private neighbor index (lanes 0..39), distributed later via shfl
    int myidx = 0;
    if (lane < TT * NN) myidx = node_neigh[(size_t)b * (TT * NN) + lane];
    const int type  = train_types[b];   // uniform-address loads (broadcast)
    const int input = train_inputs[b];

    // ---- gather neighbor type-embeddings, sum over N ----
    float4 acc = make_float4(0.f, 0.f, 0.f, 0.f);
    #pragma unroll
    for (int i = 0; i < 5; ++i) {
        const int r    = gt * NN + nb + i;
        const int node = __shfl(myidx, r);
        const float4 v = *(const float4*)(node_type_emb +
                            (size_t)node * (TT * UU) + gt * UU + sub * 4);
        acc.x += v.x; acc.y += v.y; acc.z += v.z; acc.w += v.w;
    }
    // combine the two n-halves (groups g and g^1 share t)
    acc.x += __shfl_xor(acc.x, 8);
    acc.y += __shfl_xor(acc.y, 8);
    acc.z += __shfl_xor(acc.z, 8);
    acc.w += __shfl_xor(acc.w, 8);
    if ((g & 1) == 0)
        *(float4*)(ws + gt * NTE_STRIDE + sub * 4) = acc;
    asm volatile("s_waitcnt lgkmcnt(0)" ::: "memory");

    // ---- h[t][a] = tanh( sum_u nte[t][u] * s1[u][a] ) ----
    const float* s1g = trans_s1 + (size_t)type * (UU * AA);
    {
        const int t = lane >> 4, a = lane & 15;          // a = 0..15, all t
        float hacc = 0.f;
        #pragma unroll
        for (int u = 0; u < UU; ++u)
            hacc += ws[t * NTE_STRIDE + u] * s1g[u * AA + a];
        ws[H_OFF + t * AA + a] = tanh_fast(hacc);
    }
    if (lane < 16) {                                     // a = 16..19, all t
        const int t = lane >> 2, a = 16 + (lane & 3);
        float hacc = 0.f;
        #pragma unroll
        for (int u = 0; u < UU; ++u)
            hacc += ws[t * NTE_STRIDE + u] * s1g[u * AA + a];
        ws[H_OFF + t * AA + a] = tanh_fast(hacc);
    }
    asm volatile("s_waitcnt lgkmcnt(0)" ::: "memory");

    // ---- logits[t] = h[t] . s2 ----
    if (lane < TT) {
        const float* s2g = trans_s2 + (size_t)type * AA;
        float lacc = 0.f;
        #pragma unroll
        for (int k = 0; k < 5; ++k) {
            const float4 h4 = *(const float4*)(ws + H_OFF + lane * AA + 4 * k);
            const float4 s4 = *(const float4*)(s2g + 4 * k);
            lacc += h4.x * s4.x + h4.y * s4.y + h4.z * s4.z + h4.w * s4.w;
        }
        ws[LG_OFF + lane] = lacc;
    }
    asm volatile("s_waitcnt lgkmcnt(0)" ::: "memory");

    // ---- softmax over T=4, redundantly in every lane ----
    const float4 lg = *(const float4*)(ws + LG_OFF);
    const float m  = fmaxf(fmaxf(lg.x, lg.y), fmaxf(lg.z, lg.w));
    float e0 = __expf(lg.x - m), e1 = __expf(lg.y - m),
          e2 = __expf(lg.z - m), e3 = __expf(lg.w - m);
    const float inv = 1.f / (e0 + e1 + e2 + e3);
    e0 *= inv; e1 *= inv; e2 *= inv; e3 *= inv;

    // ---- agg[u], u = lane&31 (duplicated in both half-waves) ----
    const int u = lane & 31;
    const float aggu = e0 * ws[0 * NTE_STRIDE + u] + e1 * ws[1 * NTE_STRIDE + u]
                     + e2 * ws[2 * NTE_STRIDE + u] + e3 * ws[3 * NTE_STRIDE + u];

    // ---- out = node_emb[input] + agg @ trans_w[type]; L2 normalize ----
    float4 o = make_float4(0.f, 0.f, 0.f, 0.f);
    const float* wg = trans_w + (size_t)type * (UU * DD);
    if (lane < DD / 4) {      // 50 lanes, d0 = lane*4
        o = *(const float4*)(node_emb + (size_t)input * DD + lane * 4);
        #pragma unroll 8
        for (int uu = 0; uu < UU; ++uu) {
            const float a  = __shfl(aggu, uu);
            const float4 w4 = *(const float4*)(wg + uu * DD + lane * 4);
            o.x += a * w4.x; o.y += a * w4.y; o.z += a * w4.z; o.w += a * w4.w;
        }
    }
    float sq = o.x * o.x + o.y * o.y + o.z * o.z + o.w * o.w;
    #pragma unroll
    for (int off = 1; off < 64; off <<= 1) sq += __shfl_xor(sq, off);
    const float invn = 1.f / fmaxf(sqrtf(sq), 1e-12f);
    if (lane < DD / 4) {
        const float4 r = make_float4(o.x * invn, o.y * invn, o.z * invn, o.w * invn);
        *(float4*)(out + (size_t)b * DD + lane * 4) = r;
    }
}

extern "C" void kernel_launch(void* const* d_in, const int* in_sizes, int n_in,
                              void* d_out, int out_size, void* d_ws, size_t ws_size,
                              hipStream_t stream) {
    const int*   train_inputs  = (const int*)d_in[0];
    const int*   train_types   = (const int*)d_in[1];
    const int*   node_neigh    = (const int*)d_in[2];
    const float* node_emb      = (const float*)d_in[3];
    const float* node_type_emb = (const float*)d_in[4];
    const float* trans_w       = (const float*)d_in[5];
    const float* trans_s1      = (const float*)d_in[6];
    const float* trans_s2      = (const float*)d_in[7];
    float* out = (float*)d_out;

    const int B = in_sizes[0];  // 4096
    const int grid = (B + WPB - 1) / WPB;
    gatne_kernel<<<grid, 256, 0, stream>>>(train_inputs, train_types, node_neigh,
                                           node_emb, node_type_emb, trans_w,
                                           trans_s1, trans_s2, out, B);
}